// Round 2
// baseline (154.084 us; speedup 1.0000x reference)
//
#include <hip/hip_runtime.h>
#include <math.h>

// Tiles: B*NTH*NTW = 64*56*56
constexpr int TT = 64 * 56 * 56;   // 200704
// M = 8 slots, DF = 8 flux dims, output row = 2 + 8 + 1 = 11 floats
// out per tile = 8*11 = 88 floats = 22 float4 (tile base 352B, 16B-aligned)

__global__ __launch_bounds__(256) void mvd_match_kernel(
    const float4* __restrict__ el4,   // est_locs  [TT*4] float4
    const float*  __restrict__ tl,    // true_locs [TT*16] float
    const float4* __restrict__ tf4,   // true_fluxes [TT*16] float4
    const int*    __restrict__ en_,   // est_n_sources [TT]
    const int*    __restrict__ tn_,   // true_n_sources [TT]
    float4*       __restrict__ out4)  // out [TT*22] float4
{
#pragma clang fp contract(off)
    const int t = blockIdx.x * blockDim.x + threadIdx.x;
    if (t >= TT) return;

    const int en = en_[t];
    const int tn = tn_[t];

    const float4* tl4 = (const float4*)tl;
    float4 ea = el4[t * 4 + 0], eb = el4[t * 4 + 1];
    float4 ec = el4[t * 4 + 2], ed = el4[t * 4 + 3];
    float4 ta = tl4[t * 4 + 0], tb = tl4[t * 4 + 1];
    float4 tc = tl4[t * 4 + 2], td = tl4[t * 4 + 3];

    // unpack (x,y) per slot; apply FAR=100 mask for distance computation
    float mex[8], mey[8], mtx[8], mty[8];
    {
        const float exs[8] = {ea.x, ea.z, eb.x, eb.z, ec.x, ec.z, ed.x, ed.z};
        const float eys[8] = {ea.y, ea.w, eb.y, eb.w, ec.y, ec.w, ed.y, ed.w};
        const float txs[8] = {ta.x, ta.z, tb.x, tb.z, tc.x, tc.z, td.x, td.z};
        const float tys[8] = {ta.y, ta.w, tb.y, tb.w, tc.y, tc.w, td.y, td.w};
#pragma unroll
        for (int i = 0; i < 8; i++) {
            bool eon = i < en;
            bool ton = i < tn;
            mex[i] = eon ? exs[i] : 100.0f;
            mey[i] = eon ? eys[i] : 100.0f;
            mtx[i] = ton ? txs[i] : 100.0f;
            mty[i] = ton ? tys[i] : 100.0f;
        }
    }

    // 8x8 distances (WITH sqrt: fp32 sqrt rounding can merge values that
    // differ in squared form — numpy tie-breaks to the earlier index, so we
    // must compare the same rounded values numpy sees). HIP sqrtf is IEEE
    // correctly rounded by default (no -ffast-math) == np.sqrt bitwise.
    // Argmin: strict '<' + ascending index == numpy first-occurrence.
    float colmin[8];
    int   m1[8];   // match1[j]: best est row for true col j
    int   m2[8];   // match2[i]: best true col for est row i
#pragma unroll
    for (int j = 0; j < 8; j++) { colmin[j] = 1e30f; m1[j] = 0; }
#pragma unroll
    for (int i = 0; i < 8; i++) {
        float rmin = 1e30f;
        int   rj = 0;
#pragma unroll
        for (int j = 0; j < 8; j++) {
            float dx = mex[i] - mtx[j];
            float dy = mey[i] - mty[j];
            float dx2 = dx * dx;          // contract(off): rounds like numpy
            float dy2 = dy * dy;
            float d = sqrtf(dx2 + dy2);
            if (d < rmin) { rmin = d; rj = j; }
            if (d < colmin[j]) { colmin[j] = d; m1[j] = i; }
        }
        m2[i] = rj;
    }

    // pack match1 into 3-bit fields for dynamic lookup match1[match2[k]]
    int m1p = 0;
#pragma unroll
    for (int j = 0; j < 8; j++) m1p |= m1[j] << (3 * j);

    // one2one[k] = (match1[match2[k]] == k) && match1[k] < en && match2[k] < tn
    // scatter: row match1[k] <- true row match2[k]; ascending k, last wins
    // rowsrc: 4 bits per output row r: (8 | j) if matched from true row j
    int rowsrc = 0;
#pragma unroll
    for (int k = 0; k < 8; k++) {
        int j = m2[k];
        int m1j = (m1p >> (3 * j)) & 7;
        bool o2o = (m1j == k) && (m1[k] < en) && (m2[k] < tn);
        if (o2o) {
            int r = m1[k];
            rowsrc = (rowsrc & ~(0xF << (4 * r))) | ((8 | j) << (4 * r));
        }
    }

    // assemble output tile in registers (all static indices)
    float o[88];
#pragma unroll
    for (int q = 0; q < 88; q++) o[q] = 0.0f;

    const float2* tl2 = (const float2*)tl;
#pragma unroll
    for (int r = 0; r < 8; r++) {
        int v = (rowsrc >> (4 * r)) & 15;
        if (v & 8) {
            int j = v & 7;
            float2 p  = tl2[t * 8 + j];            // original (unmasked) true loc
            float4 f0 = tf4[t * 16 + 2 * j];       // fluxes loaded lazily
            float4 f1 = tf4[t * 16 + 2 * j + 1];
            o[11 * r + 0] = p.x;
            o[11 * r + 1] = p.y;
            o[11 * r + 2] = f0.x; o[11 * r + 3] = f0.y;
            o[11 * r + 4] = f0.z; o[11 * r + 5] = f0.w;
            o[11 * r + 6] = f1.x; o[11 * r + 7] = f1.y;
            o[11 * r + 8] = f1.z; o[11 * r + 9] = f1.w;
            o[11 * r + 10] = (j < tn) ? 1.0f : 0.0f;
        }
    }

#pragma unroll
    for (int q = 0; q < 22; q++) {
        out4[t * 22 + q] = make_float4(o[4 * q + 0], o[4 * q + 1],
                                       o[4 * q + 2], o[4 * q + 3]);
    }
}

extern "C" void kernel_launch(void* const* d_in, const int* in_sizes, int n_in,
                              void* d_out, int out_size, void* d_ws, size_t ws_size,
                              hipStream_t stream) {
    const float* est_locs    = (const float*)d_in[0];
    const float* true_locs   = (const float*)d_in[1];
    const float* true_fluxes = (const float*)d_in[2];
    const int*   est_n       = (const int*)d_in[3];
    const int*   true_n      = (const int*)d_in[4];
    float* out = (float*)d_out;

    const int threads = 256;
    const int blocks = (TT + threads - 1) / threads;  // 784
    mvd_match_kernel<<<blocks, threads, 0, stream>>>(
        (const float4*)est_locs, true_locs, (const float4*)true_fluxes,
        est_n, true_n, (float4*)out);
}

// Round 3
// 151.449 us; speedup vs baseline: 1.0174x; 1.0174x over previous
//
#include <hip/hip_runtime.h>
#include <math.h>

// Tiles: B*NTH*NTW = 64*56*56
constexpr int TT = 64 * 56 * 56;   // 200704 (== 784*256 exactly)
// M = 8 slots, DF = 8 flux dims, output row = 2 + 8 + 1 = 11 floats
// out per tile = 8*11 = 88 floats = 22 float4

// ---------------------------------------------------------------------------
// Kernel A: per-tile matching -> packed rowsrc word (4 bits/output row:
// (8|j) if row matched from true row j, else 0)
// ---------------------------------------------------------------------------
__global__ __launch_bounds__(256) void mvd_match_only(
    const float4* __restrict__ el4,   // est_locs  [TT*4] float4
    const float4* __restrict__ tl4,   // true_locs [TT*4] float4
    const int*    __restrict__ en_,
    const int*    __restrict__ tn_,
    int*          __restrict__ match) // [TT] packed rowsrc
{
#pragma clang fp contract(off)
    const int t = blockIdx.x * blockDim.x + threadIdx.x;

    const int en = en_[t];
    const int tn = tn_[t];

    float4 ea = el4[t * 4 + 0], eb = el4[t * 4 + 1];
    float4 ec = el4[t * 4 + 2], ed = el4[t * 4 + 3];
    float4 ta = tl4[t * 4 + 0], tb = tl4[t * 4 + 1];
    float4 tc = tl4[t * 4 + 2], td = tl4[t * 4 + 3];

    float mex[8], mey[8], mtx[8], mty[8];
    {
        const float exs[8] = {ea.x, ea.z, eb.x, eb.z, ec.x, ec.z, ed.x, ed.z};
        const float eys[8] = {ea.y, ea.w, eb.y, eb.w, ec.y, ec.w, ed.y, ed.w};
        const float txs[8] = {ta.x, ta.z, tb.x, tb.z, tc.x, tc.z, td.x, td.z};
        const float tys[8] = {ta.y, ta.w, tb.y, tb.w, tc.y, tc.w, td.y, td.w};
#pragma unroll
        for (int i = 0; i < 8; i++) {
            bool eon = i < en;
            bool ton = i < tn;
            mex[i] = eon ? exs[i] : 100.0f;
            mey[i] = eon ? eys[i] : 100.0f;
            mtx[i] = ton ? txs[i] : 100.0f;
            mty[i] = ton ? tys[i] : 100.0f;
        }
    }

    // sqrt REQUIRED: fp32 sqrt rounding can merge values distinct in squared
    // form; numpy argmin tie-breaks to the earlier index on the rounded
    // values. HIP sqrtf (no -ffast-math) is IEEE == np.sqrt bitwise.
    float colmin[8];
    int   m1[8], m2[8];
#pragma unroll
    for (int j = 0; j < 8; j++) { colmin[j] = 1e30f; m1[j] = 0; }
#pragma unroll
    for (int i = 0; i < 8; i++) {
        float rmin = 1e30f;
        int   rj = 0;
#pragma unroll
        for (int j = 0; j < 8; j++) {
            float dx = mex[i] - mtx[j];
            float dy = mey[i] - mty[j];
            float dx2 = dx * dx;
            float dy2 = dy * dy;
            float d = sqrtf(dx2 + dy2);
            if (d < rmin) { rmin = d; rj = j; }
            if (d < colmin[j]) { colmin[j] = d; m1[j] = i; }
        }
        m2[i] = rj;
    }

    int m1p = 0;
#pragma unroll
    for (int j = 0; j < 8; j++) m1p |= m1[j] << (3 * j);

    int rowsrc = 0;
#pragma unroll
    for (int k = 0; k < 8; k++) {
        int j = m2[k];
        int m1j = (m1p >> (3 * j)) & 7;
        bool o2o = (m1j == k) && (m1[k] < en) && (m2[k] < tn);
        if (o2o) {
            int r = m1[k];
            rowsrc = (rowsrc & ~(0xF << (4 * r))) | ((8 | j) << (4 * r));
        }
    }
    match[t] = rowsrc;
}

// ---------------------------------------------------------------------------
// Kernel B: one thread per output float4 (TT*22 threads). Coalesced stores;
// gather loads hidden by 69k waves of TLP. Matched rows always have
// indicator 1.0 (o2o implies match2[k] < tn).
// ---------------------------------------------------------------------------
__global__ __launch_bounds__(256) void mvd_write(
    const float*  __restrict__ tl,    // true_locs  [TT*16]
    const float*  __restrict__ tf,    // true_fluxes [TT*64]
    const int*    __restrict__ match, // [TT]
    float4*       __restrict__ out4)  // [TT*22]
{
    const int idx = blockIdx.x * blockDim.x + threadIdx.x;  // float4 index
    const int t = idx / 22;          // compiler emits magic-mul
    const int q = idx - t * 22;
    const int w = match[t];          // 22 adjacent lanes share -> L1 broadcast

    float res[4];
#pragma unroll
    for (int u = 0; u < 4; u++) {
        int p = 4 * q + u;           // 0..87, position within tile
        int r = (p * 94) >> 10;      // == p/11 for p in [0,88)
        int c = p - r * 11;
        int v = (w >> (4 * r)) & 15;
        float val = 0.0f;
        if (v & 8) {
            int j = v & 7;
            if (c == 10)      val = 1.0f;
            else if (c < 2)   val = tl[(t << 4) + (j << 1) + c];
            else              val = tf[(t << 6) + (j << 3) + (c - 2)];
        }
        res[u] = val;
    }
    out4[idx] = make_float4(res[0], res[1], res[2], res[3]);
}

// ---------------------------------------------------------------------------
// Fallback monolith (round-2, passing) for ws_size < TT*4
// ---------------------------------------------------------------------------
__global__ __launch_bounds__(256) void mvd_mono(
    const float4* __restrict__ el4, const float* __restrict__ tl,
    const float4* __restrict__ tf4, const int* __restrict__ en_,
    const int* __restrict__ tn_, float4* __restrict__ out4)
{
#pragma clang fp contract(off)
    const int t = blockIdx.x * blockDim.x + threadIdx.x;
    const int en = en_[t], tn = tn_[t];
    const float4* tl4 = (const float4*)tl;
    float4 ea = el4[t*4+0], eb = el4[t*4+1], ec = el4[t*4+2], ed = el4[t*4+3];
    float4 ta = tl4[t*4+0], tb = tl4[t*4+1], tc = tl4[t*4+2], td = tl4[t*4+3];
    float mex[8], mey[8], mtx[8], mty[8];
    {
        const float exs[8] = {ea.x,ea.z,eb.x,eb.z,ec.x,ec.z,ed.x,ed.z};
        const float eys[8] = {ea.y,ea.w,eb.y,eb.w,ec.y,ec.w,ed.y,ed.w};
        const float txs[8] = {ta.x,ta.z,tb.x,tb.z,tc.x,tc.z,td.x,td.z};
        const float tys[8] = {ta.y,ta.w,tb.y,tb.w,tc.y,tc.w,td.y,td.w};
#pragma unroll
        for (int i = 0; i < 8; i++) {
            mex[i] = (i < en) ? exs[i] : 100.0f;
            mey[i] = (i < en) ? eys[i] : 100.0f;
            mtx[i] = (i < tn) ? txs[i] : 100.0f;
            mty[i] = (i < tn) ? tys[i] : 100.0f;
        }
    }
    float colmin[8]; int m1[8], m2[8];
#pragma unroll
    for (int j = 0; j < 8; j++) { colmin[j] = 1e30f; m1[j] = 0; }
#pragma unroll
    for (int i = 0; i < 8; i++) {
        float rmin = 1e30f; int rj = 0;
#pragma unroll
        for (int j = 0; j < 8; j++) {
            float dx = mex[i]-mtx[j], dy = mey[i]-mty[j];
            float d = sqrtf(dx*dx + dy*dy);
            if (d < rmin) { rmin = d; rj = j; }
            if (d < colmin[j]) { colmin[j] = d; m1[j] = i; }
        }
        m2[i] = rj;
    }
    int m1p = 0;
#pragma unroll
    for (int j = 0; j < 8; j++) m1p |= m1[j] << (3*j);
    int rowsrc = 0;
#pragma unroll
    for (int k = 0; k < 8; k++) {
        int j = m2[k];
        bool o2o = (((m1p >> (3*j)) & 7) == k) && (m1[k] < en) && (m2[k] < tn);
        if (o2o) rowsrc = (rowsrc & ~(0xF << (4*m1[k]))) | ((8|j) << (4*m1[k]));
    }
    float o[88];
#pragma unroll
    for (int q = 0; q < 88; q++) o[q] = 0.0f;
    const float2* tl2 = (const float2*)tl;
#pragma unroll
    for (int r = 0; r < 8; r++) {
        int v = (rowsrc >> (4*r)) & 15;
        if (v & 8) {
            int j = v & 7;
            float2 p = tl2[t*8+j];
            float4 f0 = tf4[t*16+2*j], f1 = tf4[t*16+2*j+1];
            o[11*r+0]=p.x; o[11*r+1]=p.y;
            o[11*r+2]=f0.x; o[11*r+3]=f0.y; o[11*r+4]=f0.z; o[11*r+5]=f0.w;
            o[11*r+6]=f1.x; o[11*r+7]=f1.y; o[11*r+8]=f1.z; o[11*r+9]=f1.w;
            o[11*r+10] = (j < tn) ? 1.0f : 0.0f;
        }
    }
#pragma unroll
    for (int q = 0; q < 22; q++)
        out4[t*22+q] = make_float4(o[4*q], o[4*q+1], o[4*q+2], o[4*q+3]);
}

extern "C" void kernel_launch(void* const* d_in, const int* in_sizes, int n_in,
                              void* d_out, int out_size, void* d_ws, size_t ws_size,
                              hipStream_t stream) {
    const float* est_locs    = (const float*)d_in[0];
    const float* true_locs   = (const float*)d_in[1];
    const float* true_fluxes = (const float*)d_in[2];
    const int*   est_n       = (const int*)d_in[3];
    const int*   true_n      = (const int*)d_in[4];
    float* out = (float*)d_out;

    if (ws_size >= (size_t)TT * sizeof(int)) {
        int* match = (int*)d_ws;
        mvd_match_only<<<TT / 256, 256, 0, stream>>>(
            (const float4*)est_locs, (const float4*)true_locs,
            est_n, true_n, match);
        mvd_write<<<(TT * 22) / 256, 256, 0, stream>>>(
            true_locs, true_fluxes, match, (float4*)out);
    } else {
        mvd_mono<<<TT / 256, 256, 0, stream>>>(
            (const float4*)est_locs, true_locs, (const float4*)true_fluxes,
            est_n, true_n, (float4*)out);
    }
}